// Round 4
// baseline (970.333 us; speedup 1.0000x reference)
//
#include <hip/hip_runtime.h>
#include <hip/hip_bf16.h>
#include <stdint.h>

typedef unsigned short ushort_t;
typedef __attribute__((ext_vector_type(8))) short short8;
typedef __attribute__((ext_vector_type(4))) float f32x4;
typedef __attribute__((ext_vector_type(4))) int int4v;

#define N_NODES 20000
#define N_EDGES 320000
#define D 128
#define XSTRIDE 136   // padded LDS row stride (ushorts)

__device__ __forceinline__ float b2f(ushort_t u) {
    union { float f; uint32_t i; } v; v.i = ((uint32_t)u) << 16; return v.f;
}
__device__ __forceinline__ ushort_t f2b(float f) {
    union { float f; uint32_t i; } v; v.f = f;
    uint32_t r = v.i + 0x7FFFu + ((v.i >> 16) & 1u);
    return (ushort_t)(r >> 16);
}
// dtype-flexible scalar load: raw input arrays may be f32 or bf16 (runtime-detected)
__device__ __forceinline__ float ldf(const void* p, size_t i, bool f32) {
    return f32 ? ((const float*)p)[i] : b2f(((const ushort_t*)p)[i]);
}
// dtype-flexible 8-element A-fragment load (8 consecutive elements, 8-aligned index)
__device__ __forceinline__ short8 lda8(const void* p, size_t i, bool f32) {
    if (f32) {
        const float* fp = (const float*)p + i;
        f32x4 v0 = *(const f32x4*)fp;
        f32x4 v1 = *(const f32x4*)(fp + 4);
        short8 a;
#pragma unroll
        for (int j = 0; j < 4; ++j) {
            a[j]     = (short)f2b(v0[j]);
            a[j + 4] = (short)f2b(v1[j]);
        }
        return a;
    }
    return *(const short8*)((const ushort_t*)p + i);
}
__device__ __forceinline__ float gelu_tanh(float x) {
    float u = 0.7978845608028654f * (x + 0.044715f * x * x * x);
    u = fminf(fmaxf(u, -15.f), 15.f);
    float e = __expf(2.f * u);
    float t = (e - 1.f) / (e + 1.f);
    return 0.5f * x * (1.f + t);
}
__device__ __forceinline__ int clampi(int v, int hi) {  // [0, hi)
    return v < 0 ? 0 : (v >= hi ? hi - 1 : v);
}

// row-wise LN over 128 cols spread as x[n] on 16 lanes (same quad group)
__device__ __forceinline__ void ln8(float x[8], const float gv[8], const float bv[8]) {
    float s1 = 0.f, s2 = 0.f;
#pragma unroll
    for (int n = 0; n < 8; ++n) { s1 += x[n]; s2 += x[n] * x[n]; }
#pragma unroll
    for (int m = 1; m < 16; m <<= 1) {
        s1 += __shfl_xor(s1, m, 64);
        s2 += __shfl_xor(s2, m, 64);
    }
    float mean = s1 * (1.f / 128.f);
    float var  = fmaxf(s2 * (1.f / 128.f) - mean * mean, 0.f);
    float rs   = rsqrtf(var + 1e-5f);
#pragma unroll
    for (int n = 0; n < 8; ++n) x[n] = (x[n] - mean) * rs * gv[n] + bv[n];
}

// Detect whether float inputs are f32 (flag=1) or bf16 (flag=0).
__global__ void k_detect(const uint32_t* __restrict__ raw, int* __restrict__ flag) {
    int t = blockIdx.x * blockDim.x + threadIdx.x;   // 65536 threads
    uint32_t u = raw[t];
    int e_lo = (u >> 7)  & 0xFF;
    int e_hi = (u >> 23) & 0xFF;
    if (e_lo == 0xFF || e_hi == 0xFF) atomicOr(flag, 1);
}

// pack a small dual-dtype vector into bf16
__global__ void k_pack(const void* __restrict__ src, ushort_t* __restrict__ dst, int n,
                       const int* __restrict__ dflag) {
    const bool f32 = *dflag != 0;
    int i = blockIdx.x * blockDim.x + threadIdx.x;
    if (i < n) dst[i] = f2b(ldf(src, i, f32));
}

// Transform row-major [K x 128] weight (f32 or bf16) into MFMA B-fragment order (bf16).
__global__ void k_bfrag(const void* __restrict__ src, ushort_t* __restrict__ dst, int kblks,
                        const int* __restrict__ dflag) {
    const bool f32 = *dflag != 0;
    int g = blockIdx.x * blockDim.x + threadIdx.x;
    if (g >= kblks * 512) return;
    int kblk = g >> 9;
    int rem  = g & 511;
    int nt   = rem >> 6;
    int lane = rem & 63;
    int krow = kblk * 32 + ((lane >> 4) << 3);
    int col  = nt * 16 + (lane & 15);
    short8 v;
#pragma unroll
    for (int j = 0; j < 8; ++j) v[j] = (short)f2b(ldf(src, (size_t)(krow + j) * 128 + col, f32));
    *(short8*)(dst + (size_t)g * 8) = v;
}

// ---------------- generic GEMM (embedding + mlp_out) ----------------
// A chunks: raw input (dual-dtype, isf=1) or ws bf16 (isf=0). Biases: ALWAYS bf16 arena.
template<int NC, bool LN>
__global__ __launch_bounds__(256, 2) void k_gemm(
    const ushort_t* __restrict__ bfrag,
    const void* s0, int isf0, int st0, int ko0, int kl0,
    const void* s1, int isf1, int st1, int ko1, int kl1,
    const void* s2, int isf2, int st2, int ko2, int kl2,
    int rows,
    const ushort_t* __restrict__ bias,
    const ushort_t* __restrict__ gamma,
    const ushort_t* __restrict__ betap,
    ushort_t* out,
    const int* __restrict__ dflag)
{
    __shared__ __align__(16) ushort_t lds_b[128 * 128];
    const bool f32g = *dflag != 0;
    const int tid  = threadIdx.x;
    const int wave = tid >> 6, lane = tid & 63;
    const int quad = lane >> 4, l16 = lane & 15;
    const int row0 = blockIdx.x * 128 + wave * 32;

    f32x4 acc[2][8];
#pragma unroll
    for (int t = 0; t < 2; ++t)
#pragma unroll
        for (int n = 0; n < 8; ++n) acc[t][n] = (f32x4){0.f, 0.f, 0.f, 0.f};

    const ushort_t* bptr = bfrag;
#pragma unroll
    for (int c = 0; c < NC; ++c) {
        const void* src  = (c == 0) ? s0 : ((c == 1) ? s1 : s2);
        const bool  eff  = (((c == 0) ? isf0 : ((c == 1) ? isf1 : isf2)) != 0) && f32g;
        const int stride = (c == 0) ? st0 : ((c == 1) ? st1 : st2);
        const int koff   = (c == 0) ? ko0 : ((c == 1) ? ko1 : ko2);
        const int klen   = (c == 0) ? kl0 : ((c == 1) ? kl1 : kl2);

        if (c) __syncthreads();
        {
            const int4v* gs = (const int4v*)bptr;
            int4v* ld = (int4v*)lds_b;
            const int ngrp = klen * 16;
            for (int g = tid; g < ngrp; g += 256) ld[g] = gs[g];
        }
        __syncthreads();

        size_t aoff[2];
#pragma unroll
        for (int t = 0; t < 2; ++t) {
            int r  = row0 + t * 16 + l16;
            int rr = r < rows ? r : rows - 1;
            aoff[t] = (size_t)rr * stride + koff + quad * 8;
        }
        const int ksteps = klen >> 5;
        for (int ks = 0; ks < ksteps; ++ks) {
            short8 af[2];
#pragma unroll
            for (int t = 0; t < 2; ++t)
                af[t] = lda8(src, aoff[t] + ks * 32, eff);
#pragma unroll
            for (int n = 0; n < 8; ++n) {
                short8 bf = *(const short8*)(lds_b + (size_t)((ks * 8 + n) * 64 + lane) * 8);
                acc[0][n] = __builtin_amdgcn_mfma_f32_16x16x32_bf16(af[0], bf, acc[0][n], 0, 0, 0);
                acc[1][n] = __builtin_amdgcn_mfma_f32_16x16x32_bf16(af[1], bf, acc[1][n], 0, 0, 0);
            }
        }
        bptr += (size_t)klen * 128;
    }

    float bv[8], gv[8], btv[8];
#pragma unroll
    for (int n = 0; n < 8; ++n) {
        int col = n * 16 + l16;
        bv[n] = b2f(bias[col]);
        if (LN) { gv[n] = b2f(gamma[col]); btv[n] = b2f(betap[col]); }
    }
#pragma unroll
    for (int t = 0; t < 2; ++t) {
#pragma unroll
        for (int r = 0; r < 4; ++r) {
            int row = row0 + t * 16 + quad * 4 + r;
            float x[8];
#pragma unroll
            for (int n = 0; n < 8; ++n) x[n] = acc[t][n][r] + bv[n];
            if (LN) {
#pragma unroll
                for (int n = 0; n < 8; ++n) x[n] = gelu_tanh(x[n]);
                ln8(x, gv, btv);
            }
            if (row < rows) {
#pragma unroll
                for (int n = 0; n < 8; ++n)
                    out[(size_t)row * 128 + n * 16 + l16] = f2b(x[n]);
            }
        }
    }
}

// ---------------- fused edge pipeline: proj(K=384) -> MLP1 -> MLP2 + residual + scatter-add ----------------
// All tensor operands are ws bf16; biases bf16 arena. No dtype flag needed.
__global__ __launch_bounds__(256, 2) void k_edge_fused(
    const ushort_t* __restrict__ bf_proj,
    const ushort_t* __restrict__ bf_w0,
    const ushort_t* __restrict__ bf_w1,
    ushort_t* e_glob,
    const ushort_t* __restrict__ h,
    const int* __restrict__ senders, const int* __restrict__ receivers,
    const ushort_t* __restrict__ pb,
    const ushort_t* __restrict__ b0, const ushort_t* __restrict__ g0, const ushort_t* __restrict__ be0,
    const ushort_t* __restrict__ b1, const ushort_t* __restrict__ g1, const ushort_t* __restrict__ be1,
    float* __restrict__ aggf)
{
    __shared__ __align__(16) ushort_t lds_b[128 * 128];
    __shared__ __align__(16) ushort_t lds_x[128 * XSTRIDE];
    const int tid  = threadIdx.x;
    const int wave = tid >> 6, lane = tid & 63;
    const int quad = lane >> 4, l16 = lane & 15;
    const int row0  = blockIdx.x * 128;   // 320000 % 128 == 0: all rows valid
    const int lrow0 = wave * 32;

    f32x4 acc[2][8];
#pragma unroll
    for (int t = 0; t < 2; ++t)
#pragma unroll
        for (int n = 0; n < 8; ++n) acc[t][n] = (f32x4){0.f, 0.f, 0.f, 0.f};

    for (int c = 0; c < 3; ++c) {
        if (c) __syncthreads();
        {
            const int4v* gs = (const int4v*)(bf_proj + (size_t)c * 128 * 128);
            int4v* ld = (int4v*)lds_b;
            for (int g = tid; g < 2048; g += 256) ld[g] = gs[g];
        }
        __syncthreads();
        const ushort_t* ap[2];
#pragma unroll
        for (int t = 0; t < 2; ++t) {
            int grow = row0 + lrow0 + t * 16 + l16;
            int sr = (c == 0) ? grow
                  : clampi((c == 1) ? senders[grow] : receivers[grow], N_NODES);
            const ushort_t* src = (c == 0) ? e_glob : h;
            ap[t] = src + (size_t)sr * 128 + quad * 8;
        }
        for (int ks = 0; ks < 4; ++ks) {
            short8 af[2];
#pragma unroll
            for (int t = 0; t < 2; ++t) af[t] = *(const short8*)(ap[t] + ks * 32);
#pragma unroll
            for (int n = 0; n < 8; ++n) {
                short8 bf = *(const short8*)(lds_b + (size_t)((ks * 8 + n) * 64 + lane) * 8);
                acc[0][n] = __builtin_amdgcn_mfma_f32_16x16x32_bf16(af[0], bf, acc[0][n], 0, 0, 0);
                acc[1][n] = __builtin_amdgcn_mfma_f32_16x16x32_bf16(af[1], bf, acc[1][n], 0, 0, 0);
            }
        }
    }

    {
        float bvv[8];
#pragma unroll
        for (int n = 0; n < 8; ++n) bvv[n] = b2f(pb[n * 16 + l16]);
#pragma unroll
        for (int t = 0; t < 2; ++t)
#pragma unroll
            for (int r = 0; r < 4; ++r) {
                int lrow = lrow0 + t * 16 + quad * 4 + r;
#pragma unroll
                for (int n = 0; n < 8; ++n)
                    lds_x[lrow * XSTRIDE + n * 16 + l16] = f2b(acc[t][n][r] + bvv[n]);
            }
    }
    __syncthreads();

    // MLP layer 1
    {
        const int4v* gs = (const int4v*)bf_w0;
        int4v* ld = (int4v*)lds_b;
        for (int g = tid; g < 2048; g += 256) ld[g] = gs[g];
    }
    __syncthreads();
#pragma unroll
    for (int t = 0; t < 2; ++t)
#pragma unroll
        for (int n = 0; n < 8; ++n) acc[t][n] = (f32x4){0.f, 0.f, 0.f, 0.f};
    for (int ks = 0; ks < 4; ++ks) {
        short8 af[2];
#pragma unroll
        for (int t = 0; t < 2; ++t)
            af[t] = *(const short8*)(lds_x + (lrow0 + t * 16 + l16) * XSTRIDE + ks * 32 + quad * 8);
#pragma unroll
        for (int n = 0; n < 8; ++n) {
            short8 bf = *(const short8*)(lds_b + (size_t)((ks * 8 + n) * 64 + lane) * 8);
            acc[0][n] = __builtin_amdgcn_mfma_f32_16x16x32_bf16(af[0], bf, acc[0][n], 0, 0, 0);
            acc[1][n] = __builtin_amdgcn_mfma_f32_16x16x32_bf16(af[1], bf, acc[1][n], 0, 0, 0);
        }
    }
    {
        float bv[8], gv[8], btv[8];
#pragma unroll
        for (int n = 0; n < 8; ++n) {
            int col = n * 16 + l16;
            bv[n] = b2f(b0[col]); gv[n] = b2f(g0[col]); btv[n] = b2f(be0[col]);
        }
#pragma unroll
        for (int t = 0; t < 2; ++t)
#pragma unroll
            for (int r = 0; r < 4; ++r) {
                int lrow = lrow0 + t * 16 + quad * 4 + r;
                float x[8];
#pragma unroll
                for (int n = 0; n < 8; ++n) x[n] = gelu_tanh(acc[t][n][r] + bv[n]);
                ln8(x, gv, btv);
#pragma unroll
                for (int n = 0; n < 8; ++n)
                    lds_x[lrow * XSTRIDE + n * 16 + l16] = f2b(x[n]);
            }
    }
    __syncthreads();

    // MLP layer 2 + residual + store + scatter-add
    {
        const int4v* gs = (const int4v*)bf_w1;
        int4v* ld = (int4v*)lds_b;
        for (int g = tid; g < 2048; g += 256) ld[g] = gs[g];
    }
    __syncthreads();
#pragma unroll
    for (int t = 0; t < 2; ++t)
#pragma unroll
        for (int n = 0; n < 8; ++n) acc[t][n] = (f32x4){0.f, 0.f, 0.f, 0.f};
    for (int ks = 0; ks < 4; ++ks) {
        short8 af[2];
#pragma unroll
        for (int t = 0; t < 2; ++t)
            af[t] = *(const short8*)(lds_x + (lrow0 + t * 16 + l16) * XSTRIDE + ks * 32 + quad * 8);
#pragma unroll
        for (int n = 0; n < 8; ++n) {
            short8 bf = *(const short8*)(lds_b + (size_t)((ks * 8 + n) * 64 + lane) * 8);
            acc[0][n] = __builtin_amdgcn_mfma_f32_16x16x32_bf16(af[0], bf, acc[0][n], 0, 0, 0);
            acc[1][n] = __builtin_amdgcn_mfma_f32_16x16x32_bf16(af[1], bf, acc[1][n], 0, 0, 0);
        }
    }
    {
        float bv[8], gv[8], btv[8];
#pragma unroll
        for (int n = 0; n < 8; ++n) {
            int col = n * 16 + l16;
            bv[n] = b2f(b1[col]); gv[n] = b2f(g1[col]); btv[n] = b2f(be1[col]);
        }
#pragma unroll
        for (int t = 0; t < 2; ++t)
#pragma unroll
            for (int r = 0; r < 4; ++r) {
                int grow = row0 + lrow0 + t * 16 + quad * 4 + r;
                int rcv  = clampi(receivers[grow], N_NODES);
                float x[8];
#pragma unroll
                for (int n = 0; n < 8; ++n) x[n] = gelu_tanh(acc[t][n][r] + bv[n]);
                ln8(x, gv, btv);
#pragma unroll
                for (int n = 0; n < 8; ++n) {
                    int col = n * 16 + l16;
                    float y = b2f(e_glob[(size_t)grow * 128 + col]) + x[n];
                    e_glob[(size_t)grow * 128 + col] = f2b(y);
                    atomicAdd(aggf + (size_t)rcv * 128 + col, y);
                }
            }
    }
}

// ---------------- fused node pipeline: proj(K=256) -> MLP1 -> MLP2 + residual ----------------
__global__ __launch_bounds__(256, 2) void k_node_fused(
    const ushort_t* __restrict__ bf_proj,
    const ushort_t* __restrict__ bf_w0,
    const ushort_t* __restrict__ bf_w1,
    ushort_t* h,
    const float* __restrict__ aggf,
    const float* __restrict__ cnt,
    const ushort_t* __restrict__ pb,
    const ushort_t* __restrict__ b0, const ushort_t* __restrict__ g0, const ushort_t* __restrict__ be0,
    const ushort_t* __restrict__ b1, const ushort_t* __restrict__ g1, const ushort_t* __restrict__ be1,
    int rows)
{
    __shared__ __align__(16) ushort_t lds_b[128 * 128];
    __shared__ __align__(16) ushort_t lds_x[128 * XSTRIDE];
    const int tid  = threadIdx.x;
    const int wave = tid >> 6, lane = tid & 63;
    const int quad = lane >> 4, l16 = lane & 15;
    const int row0  = blockIdx.x * 128;
    const int lrow0 = wave * 32;

    f32x4 acc[2][8];
#pragma unroll
    for (int t = 0; t < 2; ++t)
#pragma unroll
        for (int n = 0; n < 8; ++n) acc[t][n] = (f32x4){0.f, 0.f, 0.f, 0.f};

    for (int c = 0; c < 2; ++c) {
        if (c) __syncthreads();
        {
            const int4v* gs = (const int4v*)(bf_proj + (size_t)c * 128 * 128);
            int4v* ld = (int4v*)lds_b;
            for (int g = tid; g < 2048; g += 256) ld[g] = gs[g];
        }
        __syncthreads();
        int rr[2]; float inv[2];
#pragma unroll
        for (int t = 0; t < 2; ++t) {
            int grow = row0 + lrow0 + t * 16 + l16;
            rr[t] = grow < rows ? grow : rows - 1;
            if (c == 1) { float cv = cnt[rr[t]]; inv[t] = 1.f / (cv < 1.f ? 1.f : cv); }
        }
        for (int ks = 0; ks < 4; ++ks) {
            short8 af[2];
#pragma unroll
            for (int t = 0; t < 2; ++t) {
                if (c == 0) {
                    af[t] = *(const short8*)(h + (size_t)rr[t] * 128 + quad * 8 + ks * 32);
                } else {
                    const float* fp = aggf + (size_t)rr[t] * 128 + quad * 8 + ks * 32;
                    f32x4 v0 = *(const f32x4*)fp;
                    f32x4 v1 = *(const f32x4*)(fp + 4);
                    short8 a;
#pragma unroll
                    for (int j = 0; j < 4; ++j) {
                        a[j]     = (short)f2b(v0[j] * inv[t]);
                        a[j + 4] = (short)f2b(v1[j] * inv[t]);
                    }
                    af[t] = a;
                }
            }
#pragma unroll
            for (int n = 0; n < 8; ++n) {
                short8 bf = *(const short8*)(lds_b + (size_t)((ks * 8 + n) * 64 + lane) * 8);
                acc[0][n] = __builtin_amdgcn_mfma_f32_16x16x32_bf16(af[0], bf, acc[0][n], 0, 0, 0);
                acc[1][n] = __builtin_amdgcn_mfma_f32_16x16x32_bf16(af[1], bf, acc[1][n], 0, 0, 0);
            }
        }
    }

    {
        float bvv[8];
#pragma unroll
        for (int n = 0; n < 8; ++n) bvv[n] = b2f(pb[n * 16 + l16]);
#pragma unroll
        for (int t = 0; t < 2; ++t)
#pragma unroll
            for (int r = 0; r < 4; ++r) {
                int lrow = lrow0 + t * 16 + quad * 4 + r;
#pragma unroll
                for (int n = 0; n < 8; ++n)
                    lds_x[lrow * XSTRIDE + n * 16 + l16] = f2b(acc[t][n][r] + bvv[n]);
            }
    }
    __syncthreads();

    // MLP1
    {
        const int4v* gs = (const int4v*)bf_w0;
        int4v* ld = (int4v*)lds_b;
        for (int g = tid; g < 2048; g += 256) ld[g] = gs[g];
    }
    __syncthreads();
#pragma unroll
    for (int t = 0; t < 2; ++t)
#pragma unroll
        for (int n = 0; n < 8; ++n) acc[t][n] = (f32x4){0.f, 0.f, 0.f, 0.f};
    for (int ks = 0; ks < 4; ++ks) {
        short8 af[2];
#pragma unroll
        for (int t = 0; t < 2; ++t)
            af[t] = *(const short8*)(lds_x + (lrow0 + t * 16 + l16) * XSTRIDE + ks * 32 + quad * 8);
#pragma unroll
        for (int n = 0; n < 8; ++n) {
            short8 bf = *(const short8*)(lds_b + (size_t)((ks * 8 + n) * 64 + lane) * 8);
            acc[0][n] = __builtin_amdgcn_mfma_f32_16x16x32_bf16(af[0], bf, acc[0][n], 0, 0, 0);
            acc[1][n] = __builtin_amdgcn_mfma_f32_16x16x32_bf16(af[1], bf, acc[1][n], 0, 0, 0);
        }
    }
    {
        float bv[8], gv[8], btv[8];
#pragma unroll
        for (int n = 0; n < 8; ++n) {
            int col = n * 16 + l16;
            bv[n] = b2f(b0[col]); gv[n] = b2f(g0[col]); btv[n] = b2f(be0[col]);
        }
#pragma unroll
        for (int t = 0; t < 2; ++t)
#pragma unroll
            for (int r = 0; r < 4; ++r) {
                int lrow = lrow0 + t * 16 + quad * 4 + r;
                float x[8];
#pragma unroll
                for (int n = 0; n < 8; ++n) x[n] = gelu_tanh(acc[t][n][r] + bv[n]);
                ln8(x, gv, btv);
#pragma unroll
                for (int n = 0; n < 8; ++n)
                    lds_x[lrow * XSTRIDE + n * 16 + l16] = f2b(x[n]);
            }
    }
    __syncthreads();

    // MLP2 + residual
    {
        const int4v* gs = (const int4v*)bf_w1;
        int4v* ld = (int4v*)lds_b;
        for (int g = tid; g < 2048; g += 256) ld[g] = gs[g];
    }
    __syncthreads();
#pragma unroll
    for (int t = 0; t < 2; ++t)
#pragma unroll
        for (int n = 0; n < 8; ++n) acc[t][n] = (f32x4){0.f, 0.f, 0.f, 0.f};
    for (int ks = 0; ks < 4; ++ks) {
        short8 af[2];
#pragma unroll
        for (int t = 0; t < 2; ++t)
            af[t] = *(const short8*)(lds_x + (lrow0 + t * 16 + l16) * XSTRIDE + ks * 32 + quad * 8);
#pragma unroll
        for (int n = 0; n < 8; ++n) {
            short8 bf = *(const short8*)(lds_b + (size_t)((ks * 8 + n) * 64 + lane) * 8);
            acc[0][n] = __builtin_amdgcn_mfma_f32_16x16x32_bf16(af[0], bf, acc[0][n], 0, 0, 0);
            acc[1][n] = __builtin_amdgcn_mfma_f32_16x16x32_bf16(af[1], bf, acc[1][n], 0, 0, 0);
        }
    }
    {
        float bv[8], gv[8], btv[8];
#pragma unroll
        for (int n = 0; n < 8; ++n) {
            int col = n * 16 + l16;
            bv[n] = b2f(b1[col]); gv[n] = b2f(g1[col]); btv[n] = b2f(be1[col]);
        }
#pragma unroll
        for (int t = 0; t < 2; ++t)
#pragma unroll
            for (int r = 0; r < 4; ++r) {
                int grow = row0 + lrow0 + t * 16 + quad * 4 + r;
                float x[8];
#pragma unroll
                for (int n = 0; n < 8; ++n) x[n] = gelu_tanh(acc[t][n][r] + bv[n]);
                ln8(x, gv, btv);
                if (grow < rows) {
#pragma unroll
                    for (int n = 0; n < 8; ++n) {
                        int col = n * 16 + l16;
                        float y = b2f(h[(size_t)grow * 128 + col]) + x[n];
                        h[(size_t)grow * 128 + col] = f2b(y);
                    }
                }
            }
    }
}

// e = edges @ w_edge_emb + b   (K=2); edges/w raw inputs, b from bf16 arena
__global__ void k_eedge(const void* __restrict__ edges, const void* __restrict__ w,
                        const ushort_t* __restrict__ b, ushort_t* __restrict__ e, int E,
                        const int* __restrict__ dflag) {
    const bool f32g = *dflag != 0;
    int t = blockIdx.x * blockDim.x + threadIdx.x;
    int i = t >> 4, c8 = (t & 15) << 3;
    if (i >= E) return;
    float a0 = ldf(edges, (size_t)i * 2, f32g);
    float a1 = ldf(edges, (size_t)i * 2 + 1, f32g);
    short8 v;
#pragma unroll
    for (int j = 0; j < 8; ++j) {
        int c = c8 + j;
        v[j] = (short)f2b(a0 * ldf(w, c, f32g) + a1 * ldf(w, 128 + c, f32g) + b2f(b[c]));
    }
    *(short8*)(e + (size_t)i * 128 + c8) = v;
}

__global__ void k_count(const int* __restrict__ recv, float* __restrict__ cnt, int E) {
    int i = blockIdx.x * blockDim.x + threadIdx.x;
    if (i < E) atomicAdd(&cnt[clampi(recv[i], N_NODES)], 1.0f);
}

// out[n][p] = h2[n] . proj_w[:,p] + proj_b[p],  p < 24; w/b raw inputs, out matches input dtype
__global__ void k_proj(const ushort_t* __restrict__ h2, const void* __restrict__ w,
                       const void* __restrict__ b, void* __restrict__ out, int N,
                       const int* __restrict__ dflag) {
    const bool f32g = *dflag != 0;
    int t = blockIdx.x * blockDim.x + threadIdx.x;
    int n = t / 24, p = t % 24;
    if (n >= N) return;
    float acc = ldf(b, p, f32g);
    const ushort_t* hp = h2 + (size_t)n * 128;
#pragma unroll 4
    for (int k = 0; k < 128; ++k) acc += b2f(hp[k]) * ldf(w, (size_t)k * 24 + p, f32g);
    if (f32g) ((float*)out)[(size_t)n * 24 + p] = acc;
    else      ((ushort_t*)out)[(size_t)n * 24 + p] = f2b(acc);
}

extern "C" void kernel_launch(void* const* d_in, const int* in_sizes, int n_in,
                              void* d_out, int out_size, void* d_ws, size_t ws_size,
                              hipStream_t stream) {
    const void* nodes        = d_in[0];
    const void* edges        = d_in[1];
    const int*  senders      = (const int*)d_in[2];
    const int*  receivers    = (const int*)d_in[3];
    const void* w_node_emb   = d_in[4];
    const void* b_node_emb   = d_in[5];
    const void* w_edge_emb   = d_in[6];
    const void* b_edge_emb   = d_in[7];
    const void* edge_proj_w  = d_in[8];
    const void* edge_proj_b  = d_in[9];
    const void* node_proj_w  = d_in[10];
    const void* node_proj_b  = d_in[11];
    const void* edge_mlp_w   = d_in[12];
    const void* edge_mlp_b   = d_in[13];
    const void* edge_ln_g    = d_in[14];
    const void* edge_ln_b    = d_in[15];
    const void* node_mlp_w   = d_in[16];
    const void* node_mlp_b   = d_in[17];
    const void* node_ln_g    = d_in[18];
    const void* node_ln_b    = d_in[19];
    const void* mlp_out_w    = d_in[20];
    const void* mlp_out_b    = d_in[21];
    const void* mlp_out_g    = d_in[22];
    const void* mlp_out_beta = d_in[23];
    const void* proj_w       = d_in[24];
    const void* proj_b       = d_in[25];

    char* ws = (char*)d_ws;
    ushort_t* bf_nodeemb  = (ushort_t*)ws;  ws += (size_t)288 * 128 * 2;
    ushort_t* bf_edgeproj = (ushort_t*)ws;  ws += (size_t)768 * 128 * 2;
    ushort_t* bf_nodeproj = (ushort_t*)ws;  ws += (size_t)512 * 128 * 2;
    ushort_t* bf_edgemlp  = (ushort_t*)ws;  ws += (size_t)512 * 128 * 2;
    ushort_t* bf_nodemlp  = (ushort_t*)ws;  ws += (size_t)512 * 128 * 2;
    ushort_t* bf_mlpout   = (ushort_t*)ws;  ws += (size_t)128 * 128 * 2;
    ushort_t* h    = (ushort_t*)ws;         ws += (size_t)N_NODES * D * 2;
    ushort_t* e    = (ushort_t*)ws;         ws += (size_t)N_EDGES * D * 2;
    float*    aggf = (float*)ws;            ws += (size_t)N_NODES * D * 4;
    float*    cnt  = (float*)ws;            ws += (size_t)N_NODES * 4;
    int*      flag = (int*)ws;              ws += 256;
    ushort_t* bvec = (ushort_t*)ws;         ws += (size_t)34 * 128 * 2;   // packed bf16 bias arena
    ushort_t* h2   = (ushort_t*)aggf;       // alias: aggf dead after last node layer

    hipMemsetAsync(flag, 0, 256, stream);
    k_detect<<<256, 256, 0, stream>>>((const uint32_t*)nodes, flag);

    // pack all 1-D param vectors into the bf16 arena (slots of 128):
    // 0 b_node_emb | 1 b_edge_emb | 2,3 edge_proj_b | 4,5 node_proj_b | 6..9 edge_mlp_b
    // 10..13 edge_ln_g | 14..17 edge_ln_b | 18..21 node_mlp_b | 22..25 node_ln_g
    // 26..29 node_ln_b | 30 mlp_out_b | 31 mlp_out_g | 32 mlp_out_beta
    struct Pack { const void* src; int n; int dst; };
    const Pack packs[] = {
        { b_node_emb,   128, 0  }, { b_edge_emb,   128, 1  },
        { edge_proj_b,  256, 2  }, { node_proj_b,  256, 4  },
        { edge_mlp_b,   512, 6  }, { edge_ln_g,    512, 10 }, { edge_ln_b, 512, 14 },
        { node_mlp_b,   512, 18 }, { node_ln_g,    512, 22 }, { node_ln_b, 512, 26 },
        { mlp_out_b,    128, 30 }, { mlp_out_g,    128, 31 }, { mlp_out_beta, 128, 32 },
    };
    for (const Pack& p : packs)
        k_pack<<<(p.n + 255) / 256, 256, 0, stream>>>(p.src, bvec + (size_t)p.dst * 128, p.n, flag);

    k_bfrag<<<9 * 2,  256, 0, stream>>>(w_node_emb,  bf_nodeemb,  9,  flag);
    k_bfrag<<<24 * 2, 256, 0, stream>>>(edge_proj_w, bf_edgeproj, 24, flag);
    k_bfrag<<<16 * 2, 256, 0, stream>>>(node_proj_w, bf_nodeproj, 16, flag);
    k_bfrag<<<16 * 2, 256, 0, stream>>>(edge_mlp_w,  bf_edgemlp,  16, flag);
    k_bfrag<<<16 * 2, 256, 0, stream>>>(node_mlp_w,  bf_nodemlp,  16, flag);
    k_bfrag<<<4 * 2,  256, 0, stream>>>(mlp_out_w,   bf_mlpout,   4,  flag);

    hipMemsetAsync(cnt, 0, (size_t)N_NODES * 4, stream);
    k_count<<<(N_EDGES + 255) / 256, 256, 0, stream>>>(receivers, cnt, N_EDGES);

    k_eedge<<<(N_EDGES * 16) / 256, 256, 0, stream>>>(edges, w_edge_emb, bvec + 1 * 128, e, N_EDGES, flag);
    {
        const int grid = (N_NODES + 127) / 128;
        k_gemm<3, false><<<grid, 256, 0, stream>>>(
            bf_nodeemb,
            nodes, 1, 288, 0,   128,
            nodes, 1, 288, 128, 128,
            nodes, 1, 288, 256, 32,
            N_NODES, bvec + 0 * 128, nullptr, nullptr, h, flag);
    }

    const int gridE = N_EDGES / 128;           // 2500
    const int gridN = (N_NODES + 127) / 128;   // 157

    for (int l = 0; l < 2; ++l) {
        hipMemsetAsync(aggf, 0, (size_t)N_NODES * D * 4, stream);
        k_edge_fused<<<gridE, 256, 0, stream>>>(
            bf_edgeproj + (size_t)l * 384 * 128,
            bf_edgemlp + (size_t)(l * 2 + 0) * 128 * 128,
            bf_edgemlp + (size_t)(l * 2 + 1) * 128 * 128,
            e, h, senders, receivers,
            bvec + (size_t)(2 + l) * 128,
            bvec + (size_t)(6  + l * 2) * 128,     bvec + (size_t)(10 + l * 2) * 128,     bvec + (size_t)(14 + l * 2) * 128,
            bvec + (size_t)(6  + l * 2 + 1) * 128, bvec + (size_t)(10 + l * 2 + 1) * 128, bvec + (size_t)(14 + l * 2 + 1) * 128,
            aggf);
        k_node_fused<<<gridN, 256, 0, stream>>>(
            bf_nodeproj + (size_t)l * 256 * 128,
            bf_nodemlp + (size_t)(l * 2 + 0) * 128 * 128,
            bf_nodemlp + (size_t)(l * 2 + 1) * 128 * 128,
            h, aggf, cnt,
            bvec + (size_t)(4 + l) * 128,
            bvec + (size_t)(18 + l * 2) * 128,     bvec + (size_t)(22 + l * 2) * 128,     bvec + (size_t)(26 + l * 2) * 128,
            bvec + (size_t)(18 + l * 2 + 1) * 128, bvec + (size_t)(22 + l * 2 + 1) * 128, bvec + (size_t)(26 + l * 2 + 1) * 128,
            N_NODES);
    }

    k_gemm<1, true><<<gridN, 256, 0, stream>>>(
        bf_mlpout,
        h, 0, 128, 0, 128,
        nullptr, 0, 0, 0, 0,
        nullptr, 0, 0, 0, 0,
        N_NODES, bvec + 30 * 128, bvec + 31 * 128, bvec + 32 * 128, h2, flag);
    k_proj<<<(N_NODES * 24 + 255) / 256, 256, 0, stream>>>(h2, proj_w, proj_b, d_out, N_NODES, flag);
}